// Round 16
// baseline (224.485 us; speedup 1.0000x reference)
//
#include <hip/hip_runtime.h>
#include <math.h>

typedef unsigned short u16;
typedef unsigned int   u32;
typedef __attribute__((ext_vector_type(4))) float f32x4;
typedef __attribute__((ext_vector_type(8))) short s16x8;
typedef __attribute__((ext_vector_type(4))) unsigned short u16x4;

#define B_N   2
#define S_N   2048
#define HID_N 1024
#define H_N   8
#define HKV_N 2
#define D_N   256
#define QKVW  5120   // qkv_raw row width: 2048 q | 2048 gate | 512 k | 512 v

__device__ __forceinline__ u16 f2bf(float f) {
  union { float f; u32 u; } x; x.f = f;
  u32 r = x.u + 0x7FFFu + ((x.u >> 16) & 1u);
  return (u16)(r >> 16);
}
__device__ __forceinline__ float bf2f(u16 u) {
  union { u32 u; float f; } x; x.u = ((u32)u) << 16; return x.f;
}
__device__ __forceinline__ u32 pk_bf16(float lo, float hi) {
  u32 r;
  asm("v_cvt_pk_bf16_f32 %0, %1, %2" : "=v"(r) : "v"(lo), "v"(hi));
  return r;
}
__device__ __forceinline__ void gload_lds16(const u16* g, u16* l) {
  __builtin_amdgcn_global_load_lds((const __attribute__((address_space(1))) u32*)g,
                                   (__attribute__((address_space(3))) u32*)l, 16, 0, 0);
}

// ---------------- fused fp32 -> bf16 casts (5 segments) ----------------
#define N4_HS 1048576
#define N4_WQ 1048576
#define N4_WK 131072
#define N4_WV 131072
#define N4_WO 524288
#define N4_TOT (N4_HS + N4_WQ + N4_WK + N4_WV + N4_WO)

__global__ __launch_bounds__(256)
void cast5_kernel(const float* __restrict__ hs, const float* __restrict__ wq,
                  const float* __restrict__ wk, const float* __restrict__ wv,
                  const float* __restrict__ wo, u16* __restrict__ hs_bf,
                  u16* __restrict__ wqkv_bf, u16* __restrict__ wo_bf) {
  int i = blockIdx.x * blockDim.x + threadIdx.x;
  const int stride = gridDim.x * blockDim.x;
  for (; i < N4_TOT; i += stride) {
    const float* src; u16* dst; int k;
    if (i < N4_HS)                         { src = hs; dst = hs_bf; k = i; }
    else if (i < N4_HS + N4_WQ)            { src = wq; dst = wqkv_bf; k = i - N4_HS; }
    else if (i < N4_HS + N4_WQ + N4_WK)    { src = wk; dst = wqkv_bf + 4194304; k = i - (N4_HS + N4_WQ); }
    else if (i < N4_TOT - N4_WO)           { src = wv; dst = wqkv_bf + 4718592; k = i - (N4_HS + N4_WQ + N4_WK); }
    else                                   { src = wo; dst = wo_bf; k = i - (N4_TOT - N4_WO); }
    float4 v = reinterpret_cast<const float4*>(src)[k];
    u16x4 o;
    o.x = f2bf(v.x); o.y = f2bf(v.y); o.z = f2bf(v.z); o.w = f2bf(v.w);
    reinterpret_cast<u16x4*>(dst)[k] = o;
  }
}

// ---------------- RoPE trig table ----------------
__global__ __launch_bounds__(256)
void trig_kernel(const int* __restrict__ pos, float* __restrict__ ct, float* __restrict__ st) {
  int i = blockIdx.x * blockDim.x + threadIdx.x;
  if (i >= S_N * 32) return;
  int s = i >> 5, j = i & 31;
  double inv = exp(-(double)j * (log(1.0e7) / 32.0));
  double ang = (double)pos[s] * inv;
  ct[i] = (float)cos(ang);
  st[i] = (float)sin(ang);
}

// ---------------- bf16 GEMM (r9/r11: BK=64, T2 swizzle, counted vmcnt, XCD remap) ----------------
template <int OUT_BF16>
__global__ __launch_bounds__(256, 2)
void gemm_bt_kernel(const u16* __restrict__ A, const u16* __restrict__ Bw,
                    void* __restrict__ Cout, int M, int N, int K, int bn_per_x) {
  const int x = blockIdx.x & 7;
  const int i0 = blockIdx.x >> 3;
  const int bm = i0 / bn_per_x;
  const int bn = x * bn_per_x + (i0 - bm * bn_per_x);
  const int tid = threadIdx.x;
  const int lane = tid & 63;
  const int wr = tid >> 7;
  const int wc = (tid >> 6) & 1;
  __shared__ u16 sA[2][128 * 64];
  __shared__ u16 sB[2][128 * 64];
  f32x4 acc[4][4] = {};
  const u16* Ab = A + (size_t)(bm << 7) * K;
  const u16* Bb = Bw + (size_t)(bn << 7) * K;
  const int nkt = K >> 6;

  auto stage = [&](int buf, int kt) {
    const int k0 = kt << 6;
#pragma unroll
    for (int i = 0; i < 4; ++i) {
      const int L = i * 256 + tid;
      const int r = L >> 3, s = L & 7;
      gload_lds16(Ab + (size_t)r * K + k0 + ((s ^ (r & 7)) << 3), &sA[buf][L * 8]);
    }
#pragma unroll
    for (int i = 0; i < 4; ++i) {
      const int L = i * 256 + tid;
      const int r = L >> 3, s = L & 7;
      gload_lds16(Bb + (size_t)r * K + k0 + ((s ^ (r & 7)) << 3), &sB[buf][L * 8]);
    }
  };

  stage(0, 0);
  int cur = 0;
  const int ra = (wr << 6) + (lane & 15);
  const int rb = (wc << 6) + (lane & 15);
  const int l4 = (lane >> 4);
  const int sw = lane & 7;
  for (int kt = 0; kt < nkt; ++kt) {
    if (kt + 1 < nkt) {
      stage(cur ^ 1, kt + 1);
      asm volatile("s_waitcnt vmcnt(8)" ::: "memory");
    } else {
      asm volatile("s_waitcnt vmcnt(0)" ::: "memory");
    }
    __builtin_amdgcn_s_barrier();
    const u16* sa = sA[cur];
    const u16* sb = sB[cur];
#pragma unroll
    for (int kk = 0; kk < 2; ++kk) {
      const int sl = ((kk * 4 + l4) ^ sw) << 3;
      s16x8 af[4], bfr[4];
#pragma unroll
      for (int m = 0; m < 4; ++m)
        af[m] = *reinterpret_cast<const s16x8*>(sa + (ra + m * 16) * 64 + sl);
#pragma unroll
      for (int n = 0; n < 4; ++n)
        bfr[n] = *reinterpret_cast<const s16x8*>(sb + (rb + n * 16) * 64 + sl);
#pragma unroll
      for (int m = 0; m < 4; ++m)
#pragma unroll
        for (int n = 0; n < 4; ++n)
          acc[m][n] = __builtin_amdgcn_mfma_f32_16x16x32_bf16(af[m], bfr[n], acc[m][n], 0, 0, 0);
    }
    __builtin_amdgcn_s_barrier();
    cur ^= 1;
  }
  const int row0 = (bm << 7) + (wr << 6) + ((lane >> 4) << 2);
  const int col0 = (bn << 7) + (wc << 6) + (lane & 15);
#pragma unroll
  for (int m = 0; m < 4; ++m)
#pragma unroll
    for (int n = 0; n < 4; ++n)
#pragma unroll
      for (int j = 0; j < 4; ++j) {
        size_t idx = (size_t)(row0 + m * 16 + j) * N + col0 + n * 16;
        if (OUT_BF16) ((u16*)Cout)[idx] = f2bf(acc[m][n][j]);
        else          ((float*)Cout)[idx] = acc[m][n][j];
      }
}

// ---------------- RMSNorm + RoPE for q and k ----------------
__global__ __launch_bounds__(256)
void normrope_kernel(const u16* __restrict__ qkv, const float* __restrict__ qw,
                     const float* __restrict__ kw, const float* __restrict__ ct,
                     const float* __restrict__ st, u16* __restrict__ q_r,
                     u16* __restrict__ k_r) {
  const int lane = threadIdx.x & 63;
  const int row = blockIdx.x * 4 + (threadIdx.x >> 6);
  const int nq = B_N * S_N * H_N;
  const u16* src; u16* dst; const float* w;
  int s;
  if (row < nq) {
    int h = row & 7; int bs = row >> 3; s = bs & (S_N - 1); int b = bs >> 11;
    src = qkv + (size_t)(b * S_N + s) * QKVW + h * 256;
    dst = q_r + ((size_t)(b * H_N + h) * S_N + s) * 256;
    w = qw;
  } else {
    int r2 = row - nq;
    int h = r2 & 1; int bs = r2 >> 1; s = bs & (S_N - 1); int b = bs >> 11;
    src = qkv + (size_t)(b * S_N + s) * QKVW + 4096 + h * 256;
    dst = k_r + ((size_t)(b * HKV_N + h) * S_N + s) * 256;
    w = kw;
  }
  u16x4 xv = *reinterpret_cast<const u16x4*>(src + lane * 4);
  float x0 = bf2f(xv.x), x1 = bf2f(xv.y), x2 = bf2f(xv.z), x3 = bf2f(xv.w);
  float ss = x0 * x0 + x1 * x1 + x2 * x2 + x3 * x3;
#pragma unroll
  for (int off = 1; off < 64; off <<= 1) ss += __shfl_xor(ss, off);
  float rinv = rsqrtf(ss * (1.0f / 256.0f) + 1e-6f);
  float4 wv = *reinterpret_cast<const float4*>(w + lane * 4);
  float y[4] = { x0 * rinv * wv.x, x1 * rinv * wv.y, x2 * rinv * wv.z, x3 * rinv * wv.w };
  float p[4];
  p[0] = __shfl_xor(y[0], 8);
  p[1] = __shfl_xor(y[1], 8);
  p[2] = __shfl_xor(y[2], 8);
  p[3] = __shfl_xor(y[3], 8);
  if (lane < 16) {
    const float sgn = (lane < 8) ? -1.0f : 1.0f;
    const int jb = (lane * 4) & 31;
#pragma unroll
    for (int e = 0; e < 4; ++e) {
      float c = ct[(size_t)s * 32 + jb + e];
      float sn = st[(size_t)s * 32 + jb + e];
      y[e] = y[e] * c + sgn * p[e] * sn;
    }
  }
  u16x4 ov;
  ov.x = f2bf(y[0]); ov.y = f2bf(y[1]); ov.z = f2bf(y[2]); ov.w = f2bf(y[3]);
  *reinterpret_cast<u16x4*>(dst + lane * 4) = ov;
}

// ---------------- V transpose ----------------
__global__ __launch_bounds__(256)
void vtrans_kernel(const u16* __restrict__ qkv, u16* __restrict__ vt) {
  const int bid = blockIdx.x;            // 512
  const int dt = bid & 3;
  const int stile = (bid >> 2) & 31;
  const int bh = bid >> 7;
  const int b = bh >> 1, kvh = bh & 1;
  __shared__ u16 tile[64][68];
  const int t = threadIdx.x;
  const u16* src = qkv + (size_t)(b * S_N + stile * 64) * QKVW + 4608 + kvh * 256 + dt * 64;
#pragma unroll
  for (int i = 0; i < 2; ++i) {
    int sl = i * 32 + (t >> 3);
    int d8 = (t & 7) * 8;
    s16x8 v = *reinterpret_cast<const s16x8*>(src + (size_t)sl * QKVW + d8);
    u16x4 lo = { (u16)v[0], (u16)v[1], (u16)v[2], (u16)v[3] };
    u16x4 hi = { (u16)v[4], (u16)v[5], (u16)v[6], (u16)v[7] };
    *reinterpret_cast<u16x4*>(&tile[sl][d8]) = lo;
    *reinterpret_cast<u16x4*>(&tile[sl][d8 + 4]) = hi;
  }
  __syncthreads();
#pragma unroll
  for (int i = 0; i < 2; ++i) {
    int dl = i * 32 + (t >> 3);
    int s8 = (t & 7) * 8;
    u16 tmp[8];
#pragma unroll
    for (int e = 0; e < 8; ++e) tmp[e] = tile[s8 + e][dl];
    u16x4 lo = { tmp[0], tmp[1], tmp[2], tmp[3] };
    u16x4 hi = { tmp[4], tmp[5], tmp[6], tmp[7] };
    u16* dstp = vt + ((size_t)(bh * 256 + dt * 64 + dl)) * S_N + stile * 64 + s8;
    *reinterpret_cast<u16x4*>(dstp) = lo;
    *reinterpret_cast<u16x4*>(dstp + 4) = hi;
  }
}

// ---------------- flash attention, cross-step pipelined + defer-max + exp2 ----------------
__global__ __launch_bounds__(512, 2)
void attn_kernel(const u16* __restrict__ q_r, const u16* __restrict__ k_r,
                 const u16* __restrict__ vt, const u16* __restrict__ qkv,
                 u16* __restrict__ act) {
  const int dd = blockIdx.x;             // 0..255
  const int xcd = dd & 7;
  const int idx = dd >> 3;               // 0..31
  const int combo = xcd >> 1;            // b*2+kvh
  const int within = (xcd & 1) * 32 + idx;
  const int b = combo >> 1;
  const int kvh = combo & 1;
  const int h = kvh * 4 + (within >> 4);
  const int qt = within & 15;

  const int tid = threadIdx.x;
  const int lane = tid & 63;
  const int wv = tid >> 6;               // 0..7
  const int l15 = lane & 15;
  const int l4 = lane >> 4;

  __shared__ u16 sK[2][64 * 256];        // [kv][d], swizzled 16B slots (64KB)
  __shared__ u16 sVt[2][256 * 64];       // [d][kv], swizzled (64KB)
  __shared__ u16 sP[8][2][16 * 64];      // per-wave P, dbuf, 8B slots (32KB)

  const int q0 = qt * 128 + wv * 16;
  const u16* qb = q_r + ((size_t)(b * H_N + h) * S_N + q0) * 256;
  s16x8 qf[8];
#pragma unroll
  for (int kk = 0; kk < 8; ++kk)
    qf[kk] = *reinterpret_cast<const s16x8*>(qb + (size_t)l15 * 256 + kk * 32 + l4 * 8);

  f32x4 oacc[16] = {};
  float mrow = -1e30f;
  float lrow = 0.f;

  const u16* kbase = k_r + ((size_t)(b * HKV_N + kvh) * S_N) * 256;
  const u16* vbase = vt + ((size_t)(b * HKV_N + kvh) * 256) * S_N;

  const int krow_b = tid >> 5;           // 0..15
  const int kp = tid & 31;
  const int vrow_b = tid >> 3;           // 0..63
  const int vp = tid & 7;

  auto stageK = [&](int buf, int step) {
    const int kv0 = step << 6;
#pragma unroll
    for (int i = 0; i < 4; ++i) {
      const int krow = i * 16 + krow_b;
      gload_lds16(kbase + (size_t)(kv0 + krow) * 256 + ((kp ^ (krow_b & 7)) << 3),
                  &sK[buf][i * 4096 + tid * 8]);
    }
  };
  auto stageV = [&](int buf, int step) {
    const int kv0 = step << 6;
#pragma unroll
    for (int i = 0; i < 4; ++i) {
      const int vrow = i * 64 + vrow_b;
      gload_lds16(vbase + (size_t)vrow * S_N + kv0 + ((vp ^ (vrow_b & 7)) << 3),
                  &sVt[buf][i * 4096 + tid * 8]);
    }
  };

  const float scale = 0.0625f;               // 1/sqrt(256)
  const float scale2 = 0.0625f * 1.44269504f; // scale * log2(e) -> exp2 domain
  const float THR_RAW = 128.0f;              // defer-max: growth*scale <= 8
  const int sw = l15 & 7;
  const int swp = l15 & 14;              // even XOR for 8B P slots

  auto computeQK = [&](const u16* ktile, f32x4* sacc) {
#pragma unroll
    for (int kk = 0; kk < 8; ++kk) {
      const int slot = kk * 4 + l4;
#pragma unroll
      for (int g = 0; g < 4; ++g) {
        s16x8 kf = *reinterpret_cast<const s16x8*>(
            ktile + (g * 16 + l15) * 256 + ((slot ^ sw) << 3));
        sacc[g] = __builtin_amdgcn_mfma_f32_16x16x32_bf16(kf, qf[kk], sacc[g], 0, 0, 0);
      }
    }
  };
  float alphaNext = 1.0f;
  int doRescale = 0;
  auto softmaxPack = [&](f32x4* sacc, int pb) {
    float vmax = sacc[0][0];
#pragma unroll
    for (int g = 0; g < 4; ++g)
#pragma unroll
      for (int j = 0; j < 4; ++j) vmax = fmaxf(vmax, sacc[g][j]);
    vmax = fmaxf(vmax, __shfl_xor(vmax, 16));
    vmax = fmaxf(vmax, __shfl_xor(vmax, 32));
    // T13 defer-max: only rescale when growth exceeds THR (P bounded by e^8)
    doRescale = __any(vmax - mrow > THR_RAW) ? 1 : 0;
    if (doRescale) {
      float mnew = fmaxf(mrow, vmax);
      alphaNext = exp2f((mrow - mnew) * scale2);
      mrow = mnew;
      lrow *= alphaNext;
    } else {
      alphaNext = 1.0f;
    }
    const float msc2 = mrow * scale2;
    float p[16];
#pragma unroll
    for (int g = 0; g < 4; ++g)
#pragma unroll
      for (int j = 0; j < 4; ++j)
        p[g * 4 + j] = exp2f(fmaf(sacc[g][j], scale2, -msc2));
    float r = ((p[0] + p[1]) + (p[2] + p[3])) + ((p[4] + p[5]) + (p[6] + p[7]))
            + ((p[8] + p[9]) + (p[10] + p[11])) + ((p[12] + p[13]) + (p[14] + p[15]));
    r += __shfl_xor(r, 16);
    r += __shfl_xor(r, 32);
    lrow += r;
    u16* pl = &sP[wv][pb][0];
#pragma unroll
    for (int g = 0; g < 4; ++g) {
      u32 lo = pk_bf16(p[g * 4 + 0], p[g * 4 + 1]);
      u32 hi = pk_bf16(p[g * 4 + 2], p[g * 4 + 3]);
      union { u32 w[2]; u16x4 v; } u;
      u.w[0] = lo; u.w[1] = hi;
      *reinterpret_cast<u16x4*>(pl + l15 * 64 + (((g * 4 + l4) ^ swp) << 2)) = u.v;
    }
  };

  // ---- prologue: stage K(0),V(0),K(1); QK(0); softmax+pack(0) ----
  stageK(0, 0);
  stageV(0, 0);
  stageK(1, 1);
  asm volatile("s_waitcnt vmcnt(0)" ::: "memory");
  __builtin_amdgcn_s_barrier();
  {
    f32x4 sacc[4] = {};
    computeQK(sK[0], sacc);
    softmaxPack(sacc, 0);
  }

  // ---- main loop ----
  for (int t = 0; t < 32; ++t) {
    asm volatile("s_waitcnt vmcnt(0)" ::: "memory");
    __builtin_amdgcn_s_barrier();
    if (t + 2 < 32) stageK(t & 1, t + 2);
    if (t + 1 < 32) stageV((t + 1) & 1, t + 1);

    if (doRescale) {
      float ab[4];
#pragma unroll
      for (int j = 0; j < 4; ++j) ab[j] = __shfl(alphaNext, l4 * 4 + j);
#pragma unroll
      for (int nf = 0; nf < 16; ++nf) {
        oacc[nf][0] *= ab[0]; oacc[nf][1] *= ab[1];
        oacc[nf][2] *= ab[2]; oacc[nf][3] *= ab[3];
      }
    }

    __builtin_amdgcn_s_setprio(1);
    const u16* pl = &sP[wv][t & 1][0];
    const u16* vtile = sVt[t & 1];
#pragma unroll
    for (int c = 0; c < 2; ++c) {
      s16x8 paf = *reinterpret_cast<const s16x8*>(
          pl + l15 * 64 + (((c * 8 + l4 * 2) ^ swp) << 2));
#pragma unroll
      for (int nf = 0; nf < 16; ++nf) {
        s16x8 vf = *reinterpret_cast<const s16x8*>(
            vtile + (nf * 16 + l15) * 64 + (((c * 4 + l4) ^ sw) << 3));
        oacc[nf] = __builtin_amdgcn_mfma_f32_16x16x32_bf16(paf, vf, oacc[nf], 0, 0, 0);
      }
    }
    f32x4 sacc[4] = {};
    if (t + 1 < 32) computeQK(sK[(t + 1) & 1], sacc);
    __builtin_amdgcn_s_setprio(0);

    if (t + 1 < 32) softmaxPack(sacc, (t + 1) & 1);
  }

  // epilogue: O/l, silu(gate), write activation for final GEMM
  float invl = 1.0f / lrow;
  float ib[4];
#pragma unroll
  for (int j = 0; j < 4; ++j) ib[j] = __shfl(invl, l4 * 4 + j);
#pragma unroll
  for (int nf = 0; nf < 16; ++nf) {
#pragma unroll
    for (int j = 0; j < 4; ++j) {
      const int srow = q0 + l4 * 4 + j;
      const int d = nf * 16 + l15;
      float o = oacc[nf][j] * ib[j];
      float g = bf2f(qkv[(size_t)(b * S_N + srow) * QKVW + 2048 + h * 256 + d]);
      float sg = g / (1.0f + __expf(-g));
      act[(size_t)(b * S_N + srow) * 2048 + h * 256 + d] = f2bf(o * sg);
    }
  }
}

extern "C" void kernel_launch(void* const* d_in, const int* in_sizes, int n_in,
                              void* d_out, int out_size, void* d_ws, size_t ws_size,
                              hipStream_t stream) {
  const float* hs  = (const float*)d_in[0];
  const int*   pos = (const int*)d_in[1];
  const float* Wq  = (const float*)d_in[2];
  const float* Wk  = (const float*)d_in[3];
  const float* Wv  = (const float*)d_in[4];
  const float* Wo  = (const float*)d_in[5];
  const float* qw  = (const float*)d_in[6];
  const float* kw  = (const float*)d_in[7];
  float* out = (float*)d_out;

  char* w8 = (char*)d_ws;
  u16* hs_bf   = (u16*)(w8);                    // 8,388,608 B
  u16* wqkv_bf = (u16*)(w8 + 8388608);          // 10,485,760
  u16* wo_bf   = (u16*)(w8 + 18874368);         // 4,194,304
  u16* qkv_raw = (u16*)(w8 + 23068672);         // 41,943,040
  u16* q_r     = (u16*)(w8 + 65011712);         // 16,777,216
  u16* k_r     = (u16*)(w8 + 81788928);         // 4,194,304
  u16* vt      = (u16*)(w8 + 85983232);         // 4,194,304
  u16* act     = (u16*)(w8 + 90177536);         // 16,777,216
  float* cost  = (float*)(w8 + 106954752);      // 262,144
  float* sint  = (float*)(w8 + 107216896);      // 262,144  -> total 107,479,040

  // fused input casts (hs, Wq, Wk, Wv, Wo -> bf16)
  cast5_kernel<<<2048, 256, 0, stream>>>(hs, Wq, Wk, Wv, Wo, hs_bf, wqkv_bf, wo_bf);

  trig_kernel<<<(S_N * 32) / 256, 256, 0, stream>>>(pos, cost, sint);

  // QKV+gate projection: M=4096, N=5120, K=1024 -> qkv_raw bf16
  gemm_bt_kernel<1><<<1280, 256, 0, stream>>>(hs_bf, wqkv_bf, (void*)qkv_raw,
                                              4096, 5120, 1024, 5);

  // RMSNorm + RoPE (q,k); V transpose
  normrope_kernel<<<(B_N * S_N * (H_N + HKV_N)) / 4, 256, 0, stream>>>(
      qkv_raw, qw, kw, cost, sint, q_r, k_r);
  vtrans_kernel<<<512, 256, 0, stream>>>(qkv_raw, vt);

  // attention + gating -> act bf16 (r11 pipelined + defer-max + exp2)
  attn_kernel<<<256, 512, 0, stream>>>(q_r, k_r, vt, qkv_raw, act);

  // output projection: M=4096, N=1024, K=2048 -> d_out fp32
  gemm_bt_kernel<0><<<256, 256, 0, stream>>>(act, wo_bf, (void*)out,
                                             4096, 1024, 2048, 1);
}

// Round 17
// 219.156 us; speedup vs baseline: 1.0243x; 1.0243x over previous
//
#include <hip/hip_runtime.h>
#include <math.h>

typedef unsigned short u16;
typedef unsigned int   u32;
typedef __attribute__((ext_vector_type(4))) float f32x4;
typedef __attribute__((ext_vector_type(8))) short s16x8;
typedef __attribute__((ext_vector_type(4))) unsigned short u16x4;

#define B_N   2
#define S_N   2048
#define HID_N 1024
#define H_N   8
#define HKV_N 2
#define D_N   256
#define QKVW  5120   // qkv_raw row width: 2048 q | 2048 gate | 512 k | 512 v

__device__ __forceinline__ u16 f2bf(float f) {
  union { float f; u32 u; } x; x.f = f;
  u32 r = x.u + 0x7FFFu + ((x.u >> 16) & 1u);
  return (u16)(r >> 16);
}
__device__ __forceinline__ float bf2f(u16 u) {
  union { u32 u; float f; } x; x.u = ((u32)u) << 16; return x.f;
}
__device__ __forceinline__ u32 pk_bf16(float lo, float hi) {
  u32 r;
  asm("v_cvt_pk_bf16_f32 %0, %1, %2" : "=v"(r) : "v"(lo), "v"(hi));
  return r;
}
__device__ __forceinline__ void gload_lds16(const u16* g, u16* l) {
  __builtin_amdgcn_global_load_lds((const __attribute__((address_space(1))) u32*)g,
                                   (__attribute__((address_space(3))) u32*)l, 16, 0, 0);
}

// ---------------- fused fp32 -> bf16 casts (5 segments) ----------------
#define N4_HS 1048576
#define N4_WQ 1048576
#define N4_WK 131072
#define N4_WV 131072
#define N4_WO 524288
#define N4_TOT (N4_HS + N4_WQ + N4_WK + N4_WV + N4_WO)

__global__ __launch_bounds__(256)
void cast5_kernel(const float* __restrict__ hs, const float* __restrict__ wq,
                  const float* __restrict__ wk, const float* __restrict__ wv,
                  const float* __restrict__ wo, u16* __restrict__ hs_bf,
                  u16* __restrict__ wqkv_bf, u16* __restrict__ wo_bf) {
  int i = blockIdx.x * blockDim.x + threadIdx.x;
  const int stride = gridDim.x * blockDim.x;
  for (; i < N4_TOT; i += stride) {
    const float* src; u16* dst; int k;
    if (i < N4_HS)                         { src = hs; dst = hs_bf; k = i; }
    else if (i < N4_HS + N4_WQ)            { src = wq; dst = wqkv_bf; k = i - N4_HS; }
    else if (i < N4_HS + N4_WQ + N4_WK)    { src = wk; dst = wqkv_bf + 4194304; k = i - (N4_HS + N4_WQ); }
    else if (i < N4_TOT - N4_WO)           { src = wv; dst = wqkv_bf + 4718592; k = i - (N4_HS + N4_WQ + N4_WK); }
    else                                   { src = wo; dst = wo_bf; k = i - (N4_TOT - N4_WO); }
    float4 v = reinterpret_cast<const float4*>(src)[k];
    u16x4 o;
    o.x = f2bf(v.x); o.y = f2bf(v.y); o.z = f2bf(v.z); o.w = f2bf(v.w);
    reinterpret_cast<u16x4*>(dst)[k] = o;
  }
}

// ---------------- RoPE trig table ----------------
__global__ __launch_bounds__(256)
void trig_kernel(const int* __restrict__ pos, float* __restrict__ ct, float* __restrict__ st) {
  int i = blockIdx.x * blockDim.x + threadIdx.x;
  if (i >= S_N * 32) return;
  int s = i >> 5, j = i & 31;
  double inv = exp(-(double)j * (log(1.0e7) / 32.0));
  double ang = (double)pos[s] * inv;
  ct[i] = (float)cos(ang);
  st[i] = (float)sin(ang);
}

// ---------------- bf16 GEMM (r9/r11: BK=64, T2 swizzle, counted vmcnt, XCD remap) ----------------
template <int OUT_BF16>
__global__ __launch_bounds__(256, 2)
void gemm_bt_kernel(const u16* __restrict__ A, const u16* __restrict__ Bw,
                    void* __restrict__ Cout, int M, int N, int K, int bn_per_x) {
  const int x = blockIdx.x & 7;
  const int i0 = blockIdx.x >> 3;
  const int bm = i0 / bn_per_x;
  const int bn = x * bn_per_x + (i0 - bm * bn_per_x);
  const int tid = threadIdx.x;
  const int lane = tid & 63;
  const int wr = tid >> 7;
  const int wc = (tid >> 6) & 1;
  __shared__ u16 sA[2][128 * 64];
  __shared__ u16 sB[2][128 * 64];
  f32x4 acc[4][4] = {};
  const u16* Ab = A + (size_t)(bm << 7) * K;
  const u16* Bb = Bw + (size_t)(bn << 7) * K;
  const int nkt = K >> 6;

  auto stage = [&](int buf, int kt) {
    const int k0 = kt << 6;
#pragma unroll
    for (int i = 0; i < 4; ++i) {
      const int L = i * 256 + tid;
      const int r = L >> 3, s = L & 7;
      gload_lds16(Ab + (size_t)r * K + k0 + ((s ^ (r & 7)) << 3), &sA[buf][L * 8]);
    }
#pragma unroll
    for (int i = 0; i < 4; ++i) {
      const int L = i * 256 + tid;
      const int r = L >> 3, s = L & 7;
      gload_lds16(Bb + (size_t)r * K + k0 + ((s ^ (r & 7)) << 3), &sB[buf][L * 8]);
    }
  };

  stage(0, 0);
  int cur = 0;
  const int ra = (wr << 6) + (lane & 15);
  const int rb = (wc << 6) + (lane & 15);
  const int l4 = (lane >> 4);
  const int sw = lane & 7;
  for (int kt = 0; kt < nkt; ++kt) {
    if (kt + 1 < nkt) {
      stage(cur ^ 1, kt + 1);
      asm volatile("s_waitcnt vmcnt(8)" ::: "memory");
    } else {
      asm volatile("s_waitcnt vmcnt(0)" ::: "memory");
    }
    __builtin_amdgcn_s_barrier();
    const u16* sa = sA[cur];
    const u16* sb = sB[cur];
#pragma unroll
    for (int kk = 0; kk < 2; ++kk) {
      const int sl = ((kk * 4 + l4) ^ sw) << 3;
      s16x8 af[4], bfr[4];
#pragma unroll
      for (int m = 0; m < 4; ++m)
        af[m] = *reinterpret_cast<const s16x8*>(sa + (ra + m * 16) * 64 + sl);
#pragma unroll
      for (int n = 0; n < 4; ++n)
        bfr[n] = *reinterpret_cast<const s16x8*>(sb + (rb + n * 16) * 64 + sl);
#pragma unroll
      for (int m = 0; m < 4; ++m)
#pragma unroll
        for (int n = 0; n < 4; ++n)
          acc[m][n] = __builtin_amdgcn_mfma_f32_16x16x32_bf16(af[m], bfr[n], acc[m][n], 0, 0, 0);
    }
    __builtin_amdgcn_s_barrier();
    cur ^= 1;
  }
  const int row0 = (bm << 7) + (wr << 6) + ((lane >> 4) << 2);
  const int col0 = (bn << 7) + (wc << 6) + (lane & 15);
#pragma unroll
  for (int m = 0; m < 4; ++m)
#pragma unroll
    for (int n = 0; n < 4; ++n)
#pragma unroll
      for (int j = 0; j < 4; ++j) {
        size_t idx = (size_t)(row0 + m * 16 + j) * N + col0 + n * 16;
        if (OUT_BF16) ((u16*)Cout)[idx] = f2bf(acc[m][n][j]);
        else          ((float*)Cout)[idx] = acc[m][n][j];
      }
}

// ---------------- RMSNorm + RoPE for q and k ----------------
__global__ __launch_bounds__(256)
void normrope_kernel(const u16* __restrict__ qkv, const float* __restrict__ qw,
                     const float* __restrict__ kw, const float* __restrict__ ct,
                     const float* __restrict__ st, u16* __restrict__ q_r,
                     u16* __restrict__ k_r) {
  const int lane = threadIdx.x & 63;
  const int row = blockIdx.x * 4 + (threadIdx.x >> 6);
  const int nq = B_N * S_N * H_N;
  const u16* src; u16* dst; const float* w;
  int s;
  if (row < nq) {
    int h = row & 7; int bs = row >> 3; s = bs & (S_N - 1); int b = bs >> 11;
    src = qkv + (size_t)(b * S_N + s) * QKVW + h * 256;
    dst = q_r + ((size_t)(b * H_N + h) * S_N + s) * 256;
    w = qw;
  } else {
    int r2 = row - nq;
    int h = r2 & 1; int bs = r2 >> 1; s = bs & (S_N - 1); int b = bs >> 11;
    src = qkv + (size_t)(b * S_N + s) * QKVW + 4096 + h * 256;
    dst = k_r + ((size_t)(b * HKV_N + h) * S_N + s) * 256;
    w = kw;
  }
  u16x4 xv = *reinterpret_cast<const u16x4*>(src + lane * 4);
  float x0 = bf2f(xv.x), x1 = bf2f(xv.y), x2 = bf2f(xv.z), x3 = bf2f(xv.w);
  float ss = x0 * x0 + x1 * x1 + x2 * x2 + x3 * x3;
#pragma unroll
  for (int off = 1; off < 64; off <<= 1) ss += __shfl_xor(ss, off);
  float rinv = rsqrtf(ss * (1.0f / 256.0f) + 1e-6f);
  float4 wv = *reinterpret_cast<const float4*>(w + lane * 4);
  float y[4] = { x0 * rinv * wv.x, x1 * rinv * wv.y, x2 * rinv * wv.z, x3 * rinv * wv.w };
  float p[4];
  p[0] = __shfl_xor(y[0], 8);
  p[1] = __shfl_xor(y[1], 8);
  p[2] = __shfl_xor(y[2], 8);
  p[3] = __shfl_xor(y[3], 8);
  if (lane < 16) {
    const float sgn = (lane < 8) ? -1.0f : 1.0f;
    const int jb = (lane * 4) & 31;
#pragma unroll
    for (int e = 0; e < 4; ++e) {
      float c = ct[(size_t)s * 32 + jb + e];
      float sn = st[(size_t)s * 32 + jb + e];
      y[e] = y[e] * c + sgn * p[e] * sn;
    }
  }
  u16x4 ov;
  ov.x = f2bf(y[0]); ov.y = f2bf(y[1]); ov.z = f2bf(y[2]); ov.w = f2bf(y[3]);
  *reinterpret_cast<u16x4*>(dst + lane * 4) = ov;
}

// ---------------- V transpose ----------------
__global__ __launch_bounds__(256)
void vtrans_kernel(const u16* __restrict__ qkv, u16* __restrict__ vt) {
  const int bid = blockIdx.x;            // 512
  const int dt = bid & 3;
  const int stile = (bid >> 2) & 31;
  const int bh = bid >> 7;
  const int b = bh >> 1, kvh = bh & 1;
  __shared__ u16 tile[64][68];
  const int t = threadIdx.x;
  const u16* src = qkv + (size_t)(b * S_N + stile * 64) * QKVW + 4608 + kvh * 256 + dt * 64;
#pragma unroll
  for (int i = 0; i < 2; ++i) {
    int sl = i * 32 + (t >> 3);
    int d8 = (t & 7) * 8;
    s16x8 v = *reinterpret_cast<const s16x8*>(src + (size_t)sl * QKVW + d8);
    u16x4 lo = { (u16)v[0], (u16)v[1], (u16)v[2], (u16)v[3] };
    u16x4 hi = { (u16)v[4], (u16)v[5], (u16)v[6], (u16)v[7] };
    *reinterpret_cast<u16x4*>(&tile[sl][d8]) = lo;
    *reinterpret_cast<u16x4*>(&tile[sl][d8 + 4]) = hi;
  }
  __syncthreads();
#pragma unroll
  for (int i = 0; i < 2; ++i) {
    int dl = i * 32 + (t >> 3);
    int s8 = (t & 7) * 8;
    u16 tmp[8];
#pragma unroll
    for (int e = 0; e < 8; ++e) tmp[e] = tile[s8 + e][dl];
    u16x4 lo = { tmp[0], tmp[1], tmp[2], tmp[3] };
    u16x4 hi = { tmp[4], tmp[5], tmp[6], tmp[7] };
    u16* dstp = vt + ((size_t)(bh * 256 + dt * 64 + dl)) * S_N + stile * 64 + s8;
    *reinterpret_cast<u16x4*>(dstp) = lo;
    *reinterpret_cast<u16x4*>(dstp + 4) = hi;
  }
}

// ---------------- flash attention, cross-step pipelined (r11/r15 verified) ----------------
__global__ __launch_bounds__(512, 2)
void attn_kernel(const u16* __restrict__ q_r, const u16* __restrict__ k_r,
                 const u16* __restrict__ vt, const u16* __restrict__ qkv,
                 u16* __restrict__ act) {
  const int dd = blockIdx.x;             // 0..255
  const int xcd = dd & 7;
  const int idx = dd >> 3;               // 0..31
  const int combo = xcd >> 1;            // b*2+kvh
  const int within = (xcd & 1) * 32 + idx;
  const int b = combo >> 1;
  const int kvh = combo & 1;
  const int h = kvh * 4 + (within >> 4);
  const int qt = within & 15;

  const int tid = threadIdx.x;
  const int lane = tid & 63;
  const int wv = tid >> 6;               // 0..7
  const int l15 = lane & 15;
  const int l4 = lane >> 4;

  __shared__ u16 sK[2][64 * 256];        // [kv][d], swizzled 16B slots (64KB)
  __shared__ u16 sVt[2][256 * 64];       // [d][kv], swizzled (64KB)
  __shared__ u16 sP[8][2][16 * 64];      // per-wave P, dbuf, 8B slots (32KB)

  const int q0 = qt * 128 + wv * 16;
  const u16* qb = q_r + ((size_t)(b * H_N + h) * S_N + q0) * 256;
  s16x8 qf[8];
#pragma unroll
  for (int kk = 0; kk < 8; ++kk)
    qf[kk] = *reinterpret_cast<const s16x8*>(qb + (size_t)l15 * 256 + kk * 32 + l4 * 8);

  f32x4 oacc[16] = {};
  float mrow = -1e30f;
  float lrow = 0.f;

  const u16* kbase = k_r + ((size_t)(b * HKV_N + kvh) * S_N) * 256;
  const u16* vbase = vt + ((size_t)(b * HKV_N + kvh) * 256) * S_N;

  const int krow_b = tid >> 5;           // 0..15
  const int kp = tid & 31;
  const int vrow_b = tid >> 3;           // 0..63
  const int vp = tid & 7;

  auto stageK = [&](int buf, int step) {
    const int kv0 = step << 6;
#pragma unroll
    for (int i = 0; i < 4; ++i) {
      const int krow = i * 16 + krow_b;
      gload_lds16(kbase + (size_t)(kv0 + krow) * 256 + ((kp ^ (krow_b & 7)) << 3),
                  &sK[buf][i * 4096 + tid * 8]);
    }
  };
  auto stageV = [&](int buf, int step) {
    const int kv0 = step << 6;
#pragma unroll
    for (int i = 0; i < 4; ++i) {
      const int vrow = i * 64 + vrow_b;
      gload_lds16(vbase + (size_t)vrow * S_N + kv0 + ((vp ^ (vrow_b & 7)) << 3),
                  &sVt[buf][i * 4096 + tid * 8]);
    }
  };

  const float scale = 0.0625f;  // 1/sqrt(256)
  const int sw = l15 & 7;
  const int swp = l15 & 14;              // even XOR for 8B P slots

  auto computeQK = [&](const u16* ktile, f32x4* sacc) {
#pragma unroll
    for (int kk = 0; kk < 8; ++kk) {
      const int slot = kk * 4 + l4;
#pragma unroll
      for (int g = 0; g < 4; ++g) {
        s16x8 kf = *reinterpret_cast<const s16x8*>(
            ktile + (g * 16 + l15) * 256 + ((slot ^ sw) << 3));
        sacc[g] = __builtin_amdgcn_mfma_f32_16x16x32_bf16(kf, qf[kk], sacc[g], 0, 0, 0);
      }
    }
  };
  float alphaNext = 1.0f;
  int doRescale = 0;
  auto softmaxPack = [&](f32x4* sacc, int pb) {
    float vmax = sacc[0][0];
#pragma unroll
    for (int g = 0; g < 4; ++g)
#pragma unroll
      for (int j = 0; j < 4; ++j) vmax = fmaxf(vmax, sacc[g][j]);
    vmax = fmaxf(vmax, __shfl_xor(vmax, 16));
    vmax = fmaxf(vmax, __shfl_xor(vmax, 32));
    doRescale = __any(vmax > mrow) ? 1 : 0;
    if (doRescale) {
      float mnew = fmaxf(mrow, vmax);
      alphaNext = __expf((mrow - mnew) * scale);
      mrow = mnew;
      lrow *= alphaNext;
    } else {
      alphaNext = 1.0f;
    }
    const float msc = mrow * scale;
    float p[16];
#pragma unroll
    for (int g = 0; g < 4; ++g)
#pragma unroll
      for (int j = 0; j < 4; ++j)
        p[g * 4 + j] = __expf(fmaf(sacc[g][j], scale, -msc));
    float r = ((p[0] + p[1]) + (p[2] + p[3])) + ((p[4] + p[5]) + (p[6] + p[7]))
            + ((p[8] + p[9]) + (p[10] + p[11])) + ((p[12] + p[13]) + (p[14] + p[15]));
    r += __shfl_xor(r, 16);
    r += __shfl_xor(r, 32);
    lrow += r;
    u16* pl = &sP[wv][pb][0];
#pragma unroll
    for (int g = 0; g < 4; ++g) {
      u32 lo = pk_bf16(p[g * 4 + 0], p[g * 4 + 1]);
      u32 hi = pk_bf16(p[g * 4 + 2], p[g * 4 + 3]);
      union { u32 w[2]; u16x4 v; } u;
      u.w[0] = lo; u.w[1] = hi;
      *reinterpret_cast<u16x4*>(pl + l15 * 64 + (((g * 4 + l4) ^ swp) << 2)) = u.v;
    }
  };

  // ---- prologue: stage K(0),V(0),K(1); QK(0); softmax+pack(0) ----
  stageK(0, 0);
  stageV(0, 0);
  stageK(1, 1);
  asm volatile("s_waitcnt vmcnt(0)" ::: "memory");
  __builtin_amdgcn_s_barrier();
  {
    f32x4 sacc[4] = {};
    computeQK(sK[0], sacc);
    softmaxPack(sacc, 0);
  }

  // ---- main loop ----
  for (int t = 0; t < 32; ++t) {
    asm volatile("s_waitcnt vmcnt(0)" ::: "memory");
    __builtin_amdgcn_s_barrier();
    if (t + 2 < 32) stageK(t & 1, t + 2);
    if (t + 1 < 32) stageV((t + 1) & 1, t + 1);

    if (doRescale) {
      float ab[4];
#pragma unroll
      for (int j = 0; j < 4; ++j) ab[j] = __shfl(alphaNext, l4 * 4 + j);
#pragma unroll
      for (int nf = 0; nf < 16; ++nf) {
        oacc[nf][0] *= ab[0]; oacc[nf][1] *= ab[1];
        oacc[nf][2] *= ab[2]; oacc[nf][3] *= ab[3];
      }
    }

    __builtin_amdgcn_s_setprio(1);
    const u16* pl = &sP[wv][t & 1][0];
    const u16* vtile = sVt[t & 1];
#pragma unroll
    for (int c = 0; c < 2; ++c) {
      s16x8 paf = *reinterpret_cast<const s16x8*>(
          pl + l15 * 64 + (((c * 8 + l4 * 2) ^ swp) << 2));
#pragma unroll
      for (int nf = 0; nf < 16; ++nf) {
        s16x8 vf = *reinterpret_cast<const s16x8*>(
            vtile + (nf * 16 + l15) * 64 + (((c * 4 + l4) ^ sw) << 3));
        oacc[nf] = __builtin_amdgcn_mfma_f32_16x16x32_bf16(paf, vf, oacc[nf], 0, 0, 0);
      }
    }
    f32x4 sacc[4] = {};
    if (t + 1 < 32) computeQK(sK[(t + 1) & 1], sacc);
    __builtin_amdgcn_s_setprio(0);

    if (t + 1 < 32) softmaxPack(sacc, (t + 1) & 1);
  }

  // epilogue: O/l, silu(gate), write activation for final GEMM
  float invl = 1.0f / lrow;
  float ib[4];
#pragma unroll
  for (int j = 0; j < 4; ++j) ib[j] = __shfl(invl, l4 * 4 + j);
#pragma unroll
  for (int nf = 0; nf < 16; ++nf) {
#pragma unroll
    for (int j = 0; j < 4; ++j) {
      const int srow = q0 + l4 * 4 + j;
      const int d = nf * 16 + l15;
      float o = oacc[nf][j] * ib[j];
      float g = bf2f(qkv[(size_t)(b * S_N + srow) * QKVW + 2048 + h * 256 + d]);
      float sg = g / (1.0f + __expf(-g));
      act[(size_t)(b * S_N + srow) * 2048 + h * 256 + d] = f2bf(o * sg);
    }
  }
}

extern "C" void kernel_launch(void* const* d_in, const int* in_sizes, int n_in,
                              void* d_out, int out_size, void* d_ws, size_t ws_size,
                              hipStream_t stream) {
  const float* hs  = (const float*)d_in[0];
  const int*   pos = (const int*)d_in[1];
  const float* Wq  = (const float*)d_in[2];
  const float* Wk  = (const float*)d_in[3];
  const float* Wv  = (const float*)d_in[4];
  const float* Wo  = (const float*)d_in[5];
  const float* qw  = (const float*)d_in[6];
  const float* kw  = (const float*)d_in[7];
  float* out = (float*)d_out;

  char* w8 = (char*)d_ws;
  u16* hs_bf   = (u16*)(w8);                    // 8,388,608 B
  u16* wqkv_bf = (u16*)(w8 + 8388608);          // 10,485,760
  u16* wo_bf   = (u16*)(w8 + 18874368);         // 4,194,304
  u16* qkv_raw = (u16*)(w8 + 23068672);         // 41,943,040
  u16* q_r     = (u16*)(w8 + 65011712);         // 16,777,216
  u16* k_r     = (u16*)(w8 + 81788928);         // 4,194,304
  u16* vt      = (u16*)(w8 + 85983232);         // 4,194,304
  u16* act     = (u16*)(w8 + 90177536);         // 16,777,216
  float* cost  = (float*)(w8 + 106954752);      // 262,144
  float* sint  = (float*)(w8 + 107216896);      // 262,144  -> total 107,479,040

  // fused input casts (hs, Wq, Wk, Wv, Wo -> bf16)
  cast5_kernel<<<2048, 256, 0, stream>>>(hs, Wq, Wk, Wv, Wo, hs_bf, wqkv_bf, wo_bf);

  trig_kernel<<<(S_N * 32) / 256, 256, 0, stream>>>(pos, cost, sint);

  // QKV+gate projection: M=4096, N=5120, K=1024 -> qkv_raw bf16
  gemm_bt_kernel<1><<<1280, 256, 0, stream>>>(hs_bf, wqkv_bf, (void*)qkv_raw,
                                              4096, 5120, 1024, 5);

  // RMSNorm + RoPE (q,k); V transpose
  normrope_kernel<<<(B_N * S_N * (H_N + HKV_N)) / 4, 256, 0, stream>>>(
      qkv_raw, qw, kw, cost, sint, q_r, k_r);
  vtrans_kernel<<<512, 256, 0, stream>>>(qkv_raw, vt);

  // attention + gating -> act bf16 (r11/r15 pipelined structure)
  attn_kernel<<<256, 512, 0, stream>>>(q_r, k_r, vt, qkv_raw, act);

  // output projection: M=4096, N=1024, K=2048 -> d_out fp32
  gemm_bt_kernel<0><<<256, 256, 0, stream>>>(act, wo_bf, (void*)out,
                                             4096, 1024, 2048, 1);
}